// Round 1
// baseline (8238.090 us; speedup 1.0000x reference)
//
#include <hip/hip_runtime.h>

// sizes
#define NV 32000
#define NE 512
#define NH 512
#define ND 2048
#define NA 128
#define NB 32
#define NS 49
#define NT 64

// ws offsets (in floats)
#define WS_PROJ   0          // [32][49][128]
#define WS_G      200704     // [32][2048]
#define WS_HBUF   266240     // [2][32][512]
#define WS_CBUF   299008     // [2][32][512]
#define WS_CTXE   331776     // [32][512]
#define WS_XRAW   348160     // [32][512]
#define WS_GATES  364544     // [32][2048]
#define WS_WIMGT  430080     // [2048][128]
#define WS_WHIDT  692224     // [512][128]
#define WS_WCTXT  757760     // [2048][512]
#define WS_WMIXT  1806336    // [1024][512]
#define WS_WIHT   2330624    // [512][2048]
#define WS_WHHT   3379200    // [512][2048]
#define WS_H2BF   4427776    // ushort [2048][512] (occupies 524288 floats)
#define WS_WBF    4952064    // ushort [32000][512] (occupies 8192000 floats)

typedef __attribute__((ext_vector_type(8))) short v8s;
typedef __attribute__((ext_vector_type(4))) float v4f;

__device__ __forceinline__ float fsig(float x) {
    x = fminf(fmaxf(x, -30.f), 30.f);
    return 1.f / (1.f + __expf(-x));
}
__device__ __forceinline__ float ftanh(float x) {
    x = fminf(fmaxf(x, -15.f), 15.f);
    float e = __expf(2.f * x);
    return (e - 1.f) / (e + 1.f);
}
__device__ __forceinline__ unsigned short f2bf(float f) {
    union { float f; unsigned int u; } v; v.f = f;
    unsigned int u = v.u;
    unsigned int r = (u + 0x7FFFu + ((u >> 16) & 1u)) >> 16;
    return (unsigned short)r;
}

// ---------------- one-time kernels ----------------

// out[k*R + r] = in[r*K + k]
__global__ __launch_bounds__(256) void k_transpose(const float* __restrict__ in,
                                                   float* __restrict__ out, int R, int K) {
    __shared__ float tile[32][33];
    int k0 = blockIdx.x * 32, r0 = blockIdx.y * 32;
    int tx = threadIdx.x & 31, ty = threadIdx.x >> 5;
    for (int i = 0; i < 32; i += 8) {
        int r = r0 + ty + i, k = k0 + tx;
        if (r < R && k < K) tile[ty + i][tx] = in[(size_t)r * K + k];
    }
    __syncthreads();
    for (int i = 0; i < 32; i += 8) {
        int k = k0 + ty + i, r = r0 + tx;
        if (k < K && r < R) out[(size_t)k * R + r] = tile[tx][ty + i];
    }
}

__global__ __launch_bounds__(256) void k_cast(const float* __restrict__ in,
                                              unsigned short* __restrict__ out, int n) {
    int i = (blockIdx.x * 256 + threadIdx.x) * 8;
    if (i >= n) return;
    float4 a = *(const float4*)(in + i);
    float4 b = *(const float4*)(in + i + 4);
    uint4 o;
    o.x = (unsigned)f2bf(a.x) | ((unsigned)f2bf(a.y) << 16);
    o.y = (unsigned)f2bf(a.z) | ((unsigned)f2bf(a.w) << 16);
    o.z = (unsigned)f2bf(b.x) | ((unsigned)f2bf(b.y) << 16);
    o.w = (unsigned)f2bf(b.z) | ((unsigned)f2bf(b.w) << 16);
    *(uint4*)(out + i) = o;
}

// proj[b][s][a] = sum_d img[b][s][d] * W_img[a][d]   (via W_imgT[d][a])
__global__ __launch_bounds__(128) void k_proj(const float* __restrict__ img,
                                              const float* __restrict__ WimgT,
                                              float* __restrict__ proj) {
    int b = blockIdx.x / 7, sg = blockIdx.x % 7;
    int a = threadIdx.x;
    __shared__ float im[7][128];
    float acc[7] = {0.f,0.f,0.f,0.f,0.f,0.f,0.f};
    for (int dt = 0; dt < 2048; dt += 128) {
        #pragma unroll
        for (int s = 0; s < 7; s++)
            im[s][a] = img[((size_t)(b * 49 + sg * 7 + s)) * 2048 + dt + a];
        __syncthreads();
        for (int d = 0; d < 128; d++) {
            float w = WimgT[(size_t)(dt + d) * 128 + a];
            #pragma unroll
            for (int s = 0; s < 7; s++) acc[s] += im[s][d] * w;
        }
        __syncthreads();
    }
    #pragma unroll
    for (int s = 0; s < 7; s++)
        proj[((size_t)(b * 49 + sg * 7 + s)) * 128 + a] = acc[s];
}

__global__ __launch_bounds__(256) void k_gmean(const float* __restrict__ img,
                                               float* __restrict__ g) {
    int b = blockIdx.x;
    for (int d = threadIdx.x; d < 2048; d += 256) {
        float s = 0.f;
        for (int ss = 0; ss < 49; ss++) s += img[((size_t)(b * 49 + ss)) * 2048 + d];
        g[b * 2048 + d] = s * (1.f / 49.f);
    }
}

__global__ __launch_bounds__(256) void k_h0c0(const float* __restrict__ g,
        const float* __restrict__ Wh0, const float* __restrict__ bh0,
        const float* __restrict__ Wc0, const float* __restrict__ bc0,
        float* __restrict__ h0, float* __restrict__ c0) {
    int b = blockIdx.x >> 1, m = blockIdx.x & 1;
    __shared__ float gs[2048];
    for (int d = threadIdx.x; d < 2048; d += 256) gs[d] = g[b * 2048 + d];
    __syncthreads();
    const float* W = m ? Wc0 : Wh0;
    const float* bb = m ? bc0 : bh0;
    float* out = m ? c0 : h0;
    for (int r = threadIdx.x; r < 512; r += 256) {
        float acc = 0.f;
        const float* wr = W + (size_t)r * 2048;
        for (int d = 0; d < 2048; d += 4) {
            float4 w = *(const float4*)(wr + d);
            acc += w.x * gs[d] + w.y * gs[d + 1] + w.z * gs[d + 2] + w.w * gs[d + 3];
        }
        out[b * 512 + r] = ftanh(acc + bb[r]) * 0.5f;
    }
}

// ---------------- per-step kernels ----------------

// attention: ph -> scores -> softmax -> ctx -> ctxE chunk
__global__ __launch_bounds__(256) void k_attn(const float* __restrict__ hcur,
        const float* __restrict__ proj, const float* __restrict__ img,
        const float* __restrict__ WhidT, const float* __restrict__ wscore,
        const float* __restrict__ WctxT, float* __restrict__ ctxE) {
    int b = blockIdx.x >> 2, eq = blockIdx.x & 3;
    int tid = threadIdx.x;
    __shared__ float hs[512];
    __shared__ float phh[2][128];
    __shared__ float ph[128];
    __shared__ float sc[64];
    __shared__ float wsm[64];
    __shared__ float ctxs[2048];
    hs[tid] = hcur[b * 512 + tid];
    hs[tid + 256] = hcur[b * 512 + tid + 256];
    __syncthreads();
    {   // ph[a] = sum_k h[k] * W_hid[a][k]
        int a = tid & 127, half = tid >> 7;
        float p = 0.f;
        const float* wp = WhidT + (size_t)(half * 256) * 128 + a;
        const float* hp = hs + half * 256;
        for (int k = 0; k < 256; k++) p += hp[k] * wp[(size_t)k * 128];
        phh[half][a] = p;
    }
    __syncthreads();
    if (tid < 128) ph[tid] = phh[0][tid] + phh[1][tid];
    __syncthreads();
    if (tid < 49) {
        float s = 0.f;
        const float* pr = proj + (size_t)(b * 49 + tid) * 128;
        for (int a = 0; a < 128; a++) s += ftanh(pr[a] + ph[a]) * wscore[a];
        sc[tid] = s;
    }
    __syncthreads();
    if (tid < 64) {
        float v = (tid < 49) ? sc[tid] : -1e30f;
        float m = v;
        for (int o = 32; o > 0; o >>= 1) m = fmaxf(m, __shfl_xor(m, o));
        float e = (tid < 49) ? __expf(v - m) : 0.f;
        float s = e;
        for (int o = 32; o > 0; o >>= 1) s += __shfl_xor(s, o);
        if (tid < 49) wsm[tid] = e / s;
    }
    __syncthreads();
    for (int i = 0; i < 8; i++) {
        int d = i * 256 + tid;
        float a = 0.f;
        for (int s = 0; s < 49; s++) a += wsm[s] * img[((size_t)(b * 49 + s)) * 2048 + d];
        ctxs[d] = a;
    }
    __syncthreads();
    {   // ctxE[e] = sum_d ctx[d] * W_ctx[e][d]  (via W_ctxT[d][e]) for this eq chunk
        int e = eq * 128 + (tid & 127), half = tid >> 7;
        float a = 0.f;
        const float* wp = WctxT + (size_t)(half * 1024) * 512 + e;
        const float* cp = ctxs + half * 1024;
        for (int d = 0; d < 1024; d++) a += cp[d] * wp[(size_t)d * 512];
        phh[half][tid & 127] = a;
    }
    __syncthreads();
    if (tid < 128) ctxE[b * 512 + eq * 128 + tid] = phh[0][tid] + phh[1][tid];
}

// xraw = relu([emb | ctxE] @ W_mix^T)
__global__ __launch_bounds__(256) void k_mix(const int* __restrict__ tokens,
        const float* __restrict__ embed, const float* __restrict__ ctxE,
        const float* __restrict__ WmixT, float* __restrict__ xraw, int tstep) {
    int ec = blockIdx.x >> 2, bq = blockIdx.x & 3;
    int tid = threadIdx.x;
    __shared__ float cat[8][1025];
    for (int idx = tid; idx < 8192; idx += 256) {
        int bi = idx >> 10, k = idx & 1023;
        int b = bq * 8 + bi;
        float v;
        if (k < 512) {
            int tok = tokens[b * 64 + tstep];
            v = (tok == 0) ? 0.f : embed[(size_t)tok * 512 + k];
        } else {
            v = ctxE[b * 512 + (k - 512)];
        }
        cat[bi][k] = v;
    }
    __syncthreads();
    int el = tid & 31, bi = tid >> 5;
    int e = ec * 32 + el, b = bq * 8 + bi;
    float acc = 0.f;
    for (int k = 0; k < 1024; k++) acc += cat[bi][k] * WmixT[(size_t)k * 512 + e];
    xraw[b * 512 + e] = fmaxf(acc, 0.f);
}

// LN(+gamma,beta,+emb) fused into gates GEMM: gates = xn@W_ih^T + h@W_hh^T + biases
__global__ __launch_bounds__(256) void k_gates(const float* __restrict__ xraw,
        const float* __restrict__ hcur, const int* __restrict__ tokens,
        const float* __restrict__ embed, const float* __restrict__ lng,
        const float* __restrict__ lnb, const float* __restrict__ WihT,
        const float* __restrict__ WhhT, const float* __restrict__ bih,
        const float* __restrict__ bhh, float* __restrict__ gates, int tstep) {
    int c = blockIdx.x >> 3, bq = blockIdx.x & 7;
    int tid = threadIdx.x;
    __shared__ float xs[4][513];
    __shared__ float hh[4][513];
    __shared__ float red[4][64][5];
    __shared__ float mu_s[4], rs_s[4];
    for (int idx = tid; idx < 2048; idx += 256) {
        int bi = idx >> 9, k = idx & 511;
        xs[bi][k] = xraw[(bq * 4 + bi) * 512 + k];
        hh[bi][k] = hcur[(bq * 4 + bi) * 512 + k];
    }
    __syncthreads();
    {   // LN stats per b (one wave per bi)
        int bi = tid >> 6, l = tid & 63;
        float s = 0.f, s2 = 0.f;
        for (int k = l; k < 512; k += 64) { float v = xs[bi][k]; s += v; s2 += v * v; }
        for (int o = 32; o > 0; o >>= 1) { s += __shfl_xor(s, o); s2 += __shfl_xor(s2, o); }
        if (l == 0) {
            float mu = s * (1.f / 512.f);
            float var = s2 * (1.f / 512.f) - mu * mu;
            mu_s[bi] = mu; rs_s[bi] = rsqrtf(var + 1e-5f);
        }
    }
    __syncthreads();
    for (int idx = tid; idx < 2048; idx += 256) {
        int bi = idx >> 9, k = idx & 511;
        int b = bq * 4 + bi;
        int tok = tokens[b * 64 + tstep];
        float emb = (tok == 0) ? 0.f : embed[(size_t)tok * 512 + k];
        xs[bi][k] = (xs[bi][k] - mu_s[bi]) * rs_s[bi] * lng[k] + lnb[k] + emb;
    }
    __syncthreads();
    int r = tid & 63, kq = tid >> 6;
    int R = c * 64 + r;
    float acc[4] = {0.f, 0.f, 0.f, 0.f};
    for (int k = kq * 128; k < kq * 128 + 128; k++) {
        float wi = WihT[(size_t)k * 2048 + R];
        float wh = WhhT[(size_t)k * 2048 + R];
        #pragma unroll
        for (int bi = 0; bi < 4; bi++) acc[bi] += wi * xs[bi][k] + wh * hh[bi][k];
    }
    #pragma unroll
    for (int bi = 0; bi < 4; bi++) red[kq][r][bi] = acc[bi];
    __syncthreads();
    {
        int rr = tid & 63, bi = tid >> 6;
        float s = red[0][rr][bi] + red[1][rr][bi] + red[2][rr][bi] + red[3][rr][bi];
        int RR = c * 64 + rr;
        s += bih[RR] + bhh[RR];
        gates[(bq * 4 + bi) * 2048 + RR] = s;
    }
}

__global__ __launch_bounds__(128) void k_cell(const float* __restrict__ gates,
        const float* __restrict__ ccur, float* __restrict__ cnxt,
        float* __restrict__ hnxt, unsigned short* __restrict__ h2bf, int tstep) {
    int b = blockIdx.x;
    for (int j = threadIdx.x; j < 512; j += 128) {
        float gi = gates[b * 2048 + j];
        float gf = gates[b * 2048 + 512 + j];
        float gg = gates[b * 2048 + 1024 + j];
        float go = gates[b * 2048 + 1536 + j];
        float c2 = fsig(gf) * ccur[b * 512 + j] + fsig(gi) * ftanh(gg);
        float h2 = fsig(go) * ftanh(c2);
        cnxt[b * 512 + j] = c2;
        hnxt[b * 512 + j] = h2;
        h2bf[(size_t)(tstep * 32 + b) * 512 + j] = f2bf(h2);
    }
}

// ---------------- deferred head: [2048 x 32000 x 512] bf16 MFMA GEMM ----------------
__global__ __launch_bounds__(256) void k_head(const unsigned short* __restrict__ h2bf,
        const unsigned short* __restrict__ Wbf, float* __restrict__ out) {
    __shared__ unsigned short Al[128][72];
    __shared__ unsigned short Bl[128][72];
    int n0 = blockIdx.x * 128;   // v tile
    int m0 = blockIdx.y * 128;   // (t,b) tile
    int tid = threadIdx.x, lane = tid & 63, wid = tid >> 6;
    int wm = wid >> 1, wn = wid & 1;
    v4f acc[4][4] = {};
    for (int kt = 0; kt < 512; kt += 64) {
        __syncthreads();
        #pragma unroll
        for (int i = 0; i < 4; i++) {
            int idx = i * 256 + tid;
            int row = idx >> 3, c8 = (idx & 7) * 8;
            *(uint4*)&Al[row][c8] = *(const uint4*)&h2bf[(size_t)(m0 + row) * 512 + kt + c8];
            *(uint4*)&Bl[row][c8] = *(const uint4*)&Wbf[(size_t)(n0 + row) * 512 + kt + c8];
        }
        __syncthreads();
        #pragma unroll
        for (int kk = 0; kk < 2; kk++) {
            v8s a[4], bfr[4];
            int ko = kk * 32 + (lane >> 4) * 8;
            #pragma unroll
            for (int mi = 0; mi < 4; mi++)
                a[mi] = *(const v8s*)&Al[wm * 64 + mi * 16 + (lane & 15)][ko];
            #pragma unroll
            for (int ni = 0; ni < 4; ni++)
                bfr[ni] = *(const v8s*)&Bl[wn * 64 + ni * 16 + (lane & 15)][ko];
            #pragma unroll
            for (int mi = 0; mi < 4; mi++)
                #pragma unroll
                for (int ni = 0; ni < 4; ni++)
                    acc[mi][ni] = __builtin_amdgcn_mfma_f32_16x16x32_bf16(a[mi], bfr[ni], acc[mi][ni], 0, 0, 0);
        }
    }
    int col = lane & 15, rbase = (lane >> 4) * 4;
    #pragma unroll
    for (int mi = 0; mi < 4; mi++)
        #pragma unroll
        for (int ni = 0; ni < 4; ni++)
            #pragma unroll
            for (int r = 0; r < 4; r++) {
                int m = m0 + wm * 64 + mi * 16 + rbase + r;
                int v = n0 + wn * 64 + ni * 16 + col;
                int b = m & 31, t = m >> 5;
                out[((size_t)(b * 64 + t)) * 32000 + v] = acc[mi][ni][r];
            }
}

// ---------------- launch ----------------
extern "C" void kernel_launch(void* const* d_in, const int* in_sizes, int n_in,
                              void* d_out, int out_size, void* d_ws, size_t ws_size,
                              hipStream_t stream) {
    const float* img    = (const float*)d_in[0];
    const int*   toks   = (const int*)d_in[1];
    const float* embed  = (const float*)d_in[2];
    const float* W_ctx  = (const float*)d_in[3];
    const float* W_mix  = (const float*)d_in[4];
    const float* ln_g   = (const float*)d_in[5];
    const float* ln_b   = (const float*)d_in[6];
    const float* W_ih   = (const float*)d_in[7];
    const float* W_hh   = (const float*)d_in[8];
    const float* b_ih   = (const float*)d_in[9];
    const float* b_hh   = (const float*)d_in[10];
    const float* W_head = (const float*)d_in[11];
    const float* W_img  = (const float*)d_in[12];
    const float* W_hid  = (const float*)d_in[13];
    const float* w_sc   = (const float*)d_in[14];
    const float* W_h0   = (const float*)d_in[15];
    const float* b_h0   = (const float*)d_in[16];
    const float* W_c0   = (const float*)d_in[17];
    const float* b_c0   = (const float*)d_in[18];

    float* out  = (float*)d_out;
    float* ws   = (float*)d_ws;
    float* proj = ws + WS_PROJ;
    float* g    = ws + WS_G;
    float* hbuf = ws + WS_HBUF;
    float* cbuf = ws + WS_CBUF;
    float* ctxE = ws + WS_CTXE;
    float* xraw = ws + WS_XRAW;
    float* gate = ws + WS_GATES;
    float* wimgT = ws + WS_WIMGT;
    float* whidT = ws + WS_WHIDT;
    float* wctxT = ws + WS_WCTXT;
    float* wmixT = ws + WS_WMIXT;
    float* wihT  = ws + WS_WIHT;
    float* whhT  = ws + WS_WHHT;
    unsigned short* h2bf = (unsigned short*)(ws + WS_H2BF);
    unsigned short* Wbf  = (unsigned short*)(ws + WS_WBF);

    // one-time preparation (runs every call; deterministic)
    k_transpose<<<dim3(64, 4),  256, 0, stream>>>(W_img, wimgT, 128, 2048);
    k_transpose<<<dim3(16, 4),  256, 0, stream>>>(W_hid, whidT, 128, 512);
    k_transpose<<<dim3(64, 16), 256, 0, stream>>>(W_ctx, wctxT, 512, 2048);
    k_transpose<<<dim3(32, 16), 256, 0, stream>>>(W_mix, wmixT, 512, 1024);
    k_transpose<<<dim3(16, 64), 256, 0, stream>>>(W_ih,  wihT,  2048, 512);
    k_transpose<<<dim3(16, 64), 256, 0, stream>>>(W_hh,  whhT,  2048, 512);
    k_cast<<<8000, 256, 0, stream>>>(W_head, Wbf, NV * NH);
    k_proj<<<224, 128, 0, stream>>>(img, wimgT, proj);
    k_gmean<<<32, 256, 0, stream>>>(img, g);
    k_h0c0<<<64, 256, 0, stream>>>(g, W_h0, b_h0, W_c0, b_c0, hbuf, cbuf);

    // recurrence
    for (int t = 0; t < 64; t++) {
        float* hc = hbuf + (t & 1) * (32 * 512);
        float* hn = hbuf + ((t + 1) & 1) * (32 * 512);
        float* cc = cbuf + (t & 1) * (32 * 512);
        float* cn = cbuf + ((t + 1) & 1) * (32 * 512);
        k_attn<<<128, 256, 0, stream>>>(hc, proj, img, whidT, w_sc, wctxT, ctxE);
        k_mix<<<64, 256, 0, stream>>>(toks, embed, ctxE, wmixT, xraw, t);
        k_gates<<<256, 256, 0, stream>>>(xraw, hc, toks, embed, ln_g, ln_b,
                                         wihT, whhT, b_ih, b_hh, gate, t);
        k_cell<<<32, 128, 0, stream>>>(gate, cc, cn, hn, h2bf, t);
    }

    // deferred batched head GEMM
    k_head<<<dim3(250, 16), 256, 0, stream>>>(h2bf, Wbf, out);
}